// Round 1
// baseline (1536.261 us; speedup 1.0000x reference)
//
#include <hip/hip_runtime.h>
#include <math.h>

#define KNN 16
#define EPS_F 0.001f
#define BLK 256

// ---------------- Kernel 1: per-face prep ----------------
// bary (xyz) + |bary|^2 packed as float4; unit normal; p0 (vertex 0).
__global__ __launch_bounds__(BLK) void prep_kernel(
    const float* __restrict__ verts, const int* __restrict__ faces,
    float4* __restrict__ baryq, float* __restrict__ nrm,
    float* __restrict__ p0s, int F)
{
    int f = blockIdx.x * BLK + threadIdx.x;
    if (f >= F) return;
    int i0 = faces[3*f+0], i1 = faces[3*f+1], i2 = faces[3*f+2];
    float ax = verts[3*i0+0], ay = verts[3*i0+1], az = verts[3*i0+2];
    float bx = verts[3*i1+0], by = verts[3*i1+1], bz = verts[3*i1+2];
    float cx = verts[3*i2+0], cy = verts[3*i2+1], cz = verts[3*i2+2];
    float gx = (ax + bx + cx) / 3.0f;
    float gy = (ay + by + cy) / 3.0f;
    float gz = (az + bz + cz) / 3.0f;
    float sq = gx*gx + gy*gy + gz*gz;
    baryq[f] = make_float4(gx, gy, gz, sq);
    float e1x = bx-ax, e1y = by-ay, e1z = bz-az;
    float e2x = cx-ax, e2y = cy-ay, e2z = cz-az;
    float nx = e1y*e2z - e1z*e2y;
    float ny = e1z*e2x - e1x*e2z;
    float nz = e1x*e2y - e1y*e2x;
    float len = sqrtf(nx*nx + ny*ny + nz*nz);
    float dn = fmaxf(len, 1e-12f);
    nrm[3*f+0] = nx/dn; nrm[3*f+1] = ny/dn; nrm[3*f+2] = nz/dn;
    p0s[3*f+0] = ax; p0s[3*f+1] = ay; p0s[3*f+2] = az;
}

// ---------------- Kernel 2: brute-force KNN (per j-chunk partial top-16) ----
// grid = (ceil(F/BLK), nchunk). One thread = one query; LDS-tiled candidates.
__global__ __launch_bounds__(BLK) void knn_kernel(
    const float4* __restrict__ baryq,
    float* __restrict__ cand_d, int* __restrict__ cand_i,
    int F, int chunkLen, int nchunk)
{
    __shared__ float4 sb[BLK];
    int tid = threadIdx.x;
    int qi = blockIdx.x * BLK + tid;
    bool active = qi < F;
    float4 q = active ? baryq[qi] : make_float4(0.f, 0.f, 0.f, 0.f);
    float dl[KNN]; int il[KNN];
    #pragma unroll
    for (int k = 0; k < KNN; ++k) { dl[k] = INFINITY; il[k] = 0x7fffffff; }

    int jb = blockIdx.y * chunkLen;
    int je = min(jb + chunkLen, F);
    for (int base = jb; base < je; base += BLK) {
        int j = base + tid;
        sb[tid] = (j < je) ? baryq[j] : make_float4(0.f, 0.f, 0.f, INFINITY);
        __syncthreads();
        if (active) {
            #pragma unroll 4
            for (int jj = 0; jj < BLK; ++jj) {
                float4 p = sb[jj];
                float dot3 = q.x*p.x + q.y*p.y + q.z*p.z;
                float d2 = (q.w + p.w) - 2.0f * dot3;
                int jidx = base + jj;
                // lexicographic (d2, idx) strict-less vs current worst
                if (d2 < dl[KNN-1] || (d2 == dl[KNN-1] && jidx < il[KNN-1])) {
                    dl[KNN-1] = d2; il[KNN-1] = jidx;
                    #pragma unroll
                    for (int m = KNN-1; m > 0; --m) {
                        bool sw = (dl[m] < dl[m-1]) ||
                                  (dl[m] == dl[m-1] && il[m] < il[m-1]);
                        if (sw) {
                            float td = dl[m]; dl[m] = dl[m-1]; dl[m-1] = td;
                            int   ti = il[m]; il[m] = il[m-1]; il[m-1] = ti;
                        }
                    }
                }
            }
        }
        __syncthreads();
    }
    if (active) {
        size_t off = ((size_t)qi * nchunk + blockIdx.y) * KNN;
        #pragma unroll
        for (int k = 0; k < KNN; ++k) {
            cand_d[off + k] = dl[k];
            cand_i[off + k] = il[k];
        }
    }
}

// ---------------- Kernel 3: merge chunk-partials to final top-16 ----------
__global__ __launch_bounds__(BLK) void merge_kernel(
    const float* __restrict__ cand_d, const int* __restrict__ cand_i,
    int* __restrict__ nbr, int F, int nchunk)
{
    int qi = blockIdx.x * BLK + threadIdx.x;
    if (qi >= F) return;
    float dl[KNN]; int il[KNN];
    #pragma unroll
    for (int k = 0; k < KNN; ++k) { dl[k] = INFINITY; il[k] = 0x7fffffff; }
    size_t off = (size_t)qi * nchunk * KNN;
    int n = nchunk * KNN;
    for (int t = 0; t < n; ++t) {
        float d2 = cand_d[off + t];
        int j = cand_i[off + t];
        if (d2 < dl[KNN-1] || (d2 == dl[KNN-1] && j < il[KNN-1])) {
            dl[KNN-1] = d2; il[KNN-1] = j;
            #pragma unroll
            for (int m = KNN-1; m > 0; --m) {
                bool sw = (dl[m] < dl[m-1]) ||
                          (dl[m] == dl[m-1] && il[m] < il[m-1]);
                if (sw) {
                    float td = dl[m]; dl[m] = dl[m-1]; dl[m-1] = td;
                    int   ti = il[m]; il[m] = il[m-1]; il[m-1] = ti;
                }
            }
        }
    }
    #pragma unroll
    for (int k = 0; k < KNN; ++k) nbr[(size_t)qi * KNN + k] = il[k];
}

// ---------------- Kernel 4: edge-plane penetration + weighted partial sums --
__device__ __forceinline__ bool edge_test(
    float nx, float ny, float nz, float px, float py, float pz,
    float ax, float ay, float az, float bx, float by, float bz)
{
    float denom = nx*(bx-ax) + ny*(by-ay) + nz*(bz-az);
    if (fabsf(denom) < EPS_F) return false;
    float numer = nx*(px-ax) + ny*(py-ay) + nz*(pz-az);
    float t = numer / denom;
    return (t > 0.0f) && (t < 1.0f);
}

__global__ __launch_bounds__(BLK) void pen_kernel(
    const float* __restrict__ verts, const int* __restrict__ faces,
    const float* __restrict__ prob, const int* __restrict__ nbr,
    const float* __restrict__ nrm, const float* __restrict__ p0s,
    float* __restrict__ partial, int F)
{
    int t = blockIdx.x * BLK + threadIdx.x;
    float val = 0.0f;
    int total = F * KNN;
    if (t < total) {
        int i = t >> 4;              // / KNN
        int j = nbr[t];
        if (j != i) {
            float nx = nrm[3*i+0], ny = nrm[3*i+1], nz = nrm[3*i+2];
            float px = p0s[3*i+0], py = p0s[3*i+1], pz = p0s[3*i+2];
            int j0 = faces[3*j+0], j1 = faces[3*j+1], j2 = faces[3*j+2];
            float ax = verts[3*j0+0], ay = verts[3*j0+1], az = verts[3*j0+2];
            float bx = verts[3*j1+0], by = verts[3*j1+1], bz = verts[3*j1+2];
            float cx = verts[3*j2+0], cy = verts[3*j2+1], cz = verts[3*j2+2];
            bool hit = edge_test(nx,ny,nz, px,py,pz, ax,ay,az, bx,by,bz)
                    || edge_test(nx,ny,nz, px,py,pz, bx,by,bz, cx,cy,cz)
                    || edge_test(nx,ny,nz, px,py,pz, cx,cy,cz, ax,ay,az);
            if (hit) val = prob[j];
        }
    }
    __shared__ float red[BLK];
    red[threadIdx.x] = val;
    __syncthreads();
    #pragma unroll
    for (int s = BLK/2; s > 0; s >>= 1) {
        if (threadIdx.x < s) red[threadIdx.x] += red[threadIdx.x + s];
        __syncthreads();
    }
    if (threadIdx.x == 0) partial[blockIdx.x] = red[0];
}

// ---------------- Kernel 5: final deterministic reduce ----------------
__global__ __launch_bounds__(BLK) void final_reduce(
    const float* __restrict__ partial, int n, float* __restrict__ out, int F)
{
    __shared__ float red[BLK];
    float s = 0.0f;
    for (int i = threadIdx.x; i < n; i += BLK) s += partial[i];
    red[threadIdx.x] = s;
    __syncthreads();
    #pragma unroll
    for (int st = BLK/2; st > 0; st >>= 1) {
        if (threadIdx.x < st) red[threadIdx.x] += red[threadIdx.x + st];
        __syncthreads();
    }
    if (threadIdx.x == 0) out[0] = red[0] / (float)F;
}

extern "C" void kernel_launch(void* const* d_in, const int* in_sizes, int n_in,
                              void* d_out, int out_size, void* d_ws, size_t ws_size,
                              hipStream_t stream)
{
    const float* verts = (const float*)d_in[0];
    const int*   faces = (const int*)d_in[1];
    const float* prob  = (const float*)d_in[2];
    float* out = (float*)d_out;
    int F = in_sizes[2];            // number of faces (probabilities length)

    // --- workspace carve (256B-aligned slabs) ---
    size_t off = 0;
    auto carve = [&](size_t bytes) {
        size_t cur = off;
        off += (bytes + 255) & ~(size_t)255;
        return cur;
    };
    char* w = (char*)d_ws;
    int nPenBlocks = (F * KNN + BLK - 1) / BLK;
    float4* baryq  = (float4*)(w + carve((size_t)F * sizeof(float4)));
    float*  nrm    = (float*)(w + carve((size_t)F * 3 * sizeof(float)));
    float*  p0s    = (float*)(w + carve((size_t)F * 3 * sizeof(float)));
    int*    nbr    = (int*)(w + carve((size_t)F * KNN * sizeof(int)));
    float*  partial= (float*)(w + carve((size_t)nPenBlocks * sizeof(float)));

    // choose j-chunk count from remaining workspace (8 preferred for occupancy)
    size_t perChunk = (size_t)F * KNN * (sizeof(float) + sizeof(int)) + 512;
    size_t remain = (ws_size > off) ? (ws_size - off) : 0;
    int nchunk = (int)(remain / perChunk);
    if (nchunk > 8) nchunk = 8;
    if (nchunk < 1) nchunk = 1;
    float* cand_d = (float*)(w + carve((size_t)F * KNN * nchunk * sizeof(float)));
    int*   cand_i = (int*)(w + carve((size_t)F * KNN * nchunk * sizeof(int)));

    int chunkLen = (F + nchunk - 1) / nchunk;
    int qBlocks = (F + BLK - 1) / BLK;

    prep_kernel<<<qBlocks, BLK, 0, stream>>>(verts, faces, baryq, nrm, p0s, F);
    knn_kernel<<<dim3(qBlocks, nchunk), BLK, 0, stream>>>(
        baryq, cand_d, cand_i, F, chunkLen, nchunk);
    merge_kernel<<<qBlocks, BLK, 0, stream>>>(cand_d, cand_i, nbr, F, nchunk);
    pen_kernel<<<nPenBlocks, BLK, 0, stream>>>(
        verts, faces, prob, nbr, nrm, p0s, partial, F);
    final_reduce<<<1, BLK, 0, stream>>>(partial, nPenBlocks, out, F);
}

// Round 2
// 455.439 us; speedup vs baseline: 3.3731x; 3.3731x over previous
//
#include <hip/hip_runtime.h>
#include <math.h>

#define KNN 16
#define EPS_F 0.001f
#define BLK 256

// ---------- register-resident top-16 (named scalars; rule #20: no arrays) ----
#define REP16(M) M(0) M(1) M(2) M(3) M(4) M(5) M(6) M(7) \
                 M(8) M(9) M(10) M(11) M(12) M(13) M(14) M(15)

#define T16_DECL(m) float d##m = INFINITY; int i##m = 0x7fffffff;
// all compares read OLD list values; then updates descend 15->0 so each
// position reads d_{m-1} before it is overwritten. depth-2, fully parallel.
#define T16_CMP(m)  const bool c##m = tx < d##m;
#define T16_UPD(m,p) d##m = c##p ? d##p : (c##m ? tx : d##m); \
                     i##m = c##p ? i##p : (c##m ? txi : i##m);
#define T16_INSERT() do { \
  REP16(T16_CMP) \
  T16_UPD(15,14) T16_UPD(14,13) T16_UPD(13,12) T16_UPD(12,11) \
  T16_UPD(11,10) T16_UPD(10,9)  T16_UPD(9,8)   T16_UPD(8,7)  \
  T16_UPD(7,6)   T16_UPD(6,5)   T16_UPD(5,4)   T16_UPD(4,3)  \
  T16_UPD(3,2)   T16_UPD(2,1)   T16_UPD(1,0)                 \
  d0 = c0 ? tx : d0; i0 = c0 ? txi : i0;                     \
} while (0)

// ---------------- Kernel 1: per-face prep ----------------
__global__ __launch_bounds__(BLK) void prep_kernel(
    const float* __restrict__ verts, const int* __restrict__ faces,
    float4* __restrict__ baryq, float* __restrict__ nrm,
    float* __restrict__ p0s, int F)
{
    int f = blockIdx.x * BLK + threadIdx.x;
    if (f >= F) return;
    int i0 = faces[3*f+0], i1 = faces[3*f+1], i2 = faces[3*f+2];
    float ax = verts[3*i0+0], ay = verts[3*i0+1], az = verts[3*i0+2];
    float bx = verts[3*i1+0], by = verts[3*i1+1], bz = verts[3*i1+2];
    float cx = verts[3*i2+0], cy = verts[3*i2+1], cz = verts[3*i2+2];
    float gx = (ax + bx + cx) / 3.0f;
    float gy = (ay + by + cy) / 3.0f;
    float gz = (az + bz + cz) / 3.0f;
    float sq = gx*gx + gy*gy + gz*gz;
    baryq[f] = make_float4(gx, gy, gz, sq);
    float e1x = bx-ax, e1y = by-ay, e1z = bz-az;
    float e2x = cx-ax, e2y = cy-ay, e2z = cz-az;
    float nx = e1y*e2z - e1z*e2y;
    float ny = e1z*e2x - e1x*e2z;
    float nz = e1x*e2y - e1y*e2x;
    float len = sqrtf(nx*nx + ny*ny + nz*nz);
    float dn = fmaxf(len, 1e-12f);
    nrm[3*f+0] = nx/dn; nrm[3*f+1] = ny/dn; nrm[3*f+2] = nz/dn;
    p0s[3*f+0] = ax; p0s[3*f+1] = ay; p0s[3*f+2] = az;
}

// ---------------- Kernel 2: brute-force KNN, per-chunk partial top-16 ------
// grid = (ceil(F/BLK), nchunk). 1 thread = 1 query. Candidate indices only,
// stored transposed: cand_i[(chunk*KNN + k) * F + qi]  (coalesced).
__global__ __launch_bounds__(BLK) void knn_kernel(
    const float4* __restrict__ baryq,
    int* __restrict__ cand_i,
    int F, int chunkLen, int nchunk)
{
    __shared__ float4 sb[BLK];
    int tid = threadIdx.x;
    int qi = blockIdx.x * BLK + tid;
    bool active = qi < F;
    float4 q = active ? baryq[qi] : make_float4(0.f, 0.f, 0.f, 0.f);

    REP16(T16_DECL)

    int jb = blockIdx.y * chunkLen;
    int je = min(jb + chunkLen, F);
    for (int base = jb; base < je; base += BLK) {
        int j = base + tid;
        sb[tid] = (j < je) ? baryq[j] : make_float4(0.f, 0.f, 0.f, INFINITY);
        __syncthreads();
        int lim = min(BLK, je - base);
        #pragma unroll 2
        for (int jj = 0; jj < BLK; ++jj) {
            if (jj >= lim) break;
            float4 p = sb[jj];
            float tx = (q.w + p.w) - 2.0f * (q.x*p.x + q.y*p.y + q.z*p.z);
            int txi = base + jj;
            T16_INSERT();
        }
        __syncthreads();
    }
    if (active) {
        size_t cb = (size_t)blockIdx.y * KNN * F + qi;
        #define T16_ST(m) cand_i[cb + (size_t)(m) * F] = i##m;
        REP16(T16_ST)
        #undef T16_ST
    }
}

// ---------------- Kernel 3: merge chunk partials (recompute d2) ------------
__global__ __launch_bounds__(BLK) void merge_kernel(
    const float4* __restrict__ baryq, const int* __restrict__ cand_i,
    int* __restrict__ nbr, int F, int nchunk)
{
    int qi = blockIdx.x * BLK + threadIdx.x;
    if (qi >= F) return;
    float4 q = baryq[qi];
    REP16(T16_DECL)
    int n = nchunk * KNN;
    for (int t = 0; t < n; ++t) {
        int j = cand_i[(size_t)t * F + qi];
        float tx = INFINITY;
        int txi = j;
        if (j < F) {
            float4 p = baryq[j];
            tx = (q.w + p.w) - 2.0f * (q.x*p.x + q.y*p.y + q.z*p.z);
        }
        T16_INSERT();
    }
    size_t ob = (size_t)qi * KNN;
    #define T16_STN(m) nbr[ob + (m)] = i##m;
    REP16(T16_STN)
    #undef T16_STN
}

// ---------------- Kernel 4: edge-plane penetration + partial sums ----------
__device__ __forceinline__ bool edge_test(
    float nx, float ny, float nz, float px, float py, float pz,
    float ax, float ay, float az, float bx, float by, float bz)
{
    float denom = nx*(bx-ax) + ny*(by-ay) + nz*(bz-az);
    if (fabsf(denom) < EPS_F) return false;
    float numer = nx*(px-ax) + ny*(py-ay) + nz*(pz-az);
    float t = numer / denom;
    return (t > 0.0f) && (t < 1.0f);
}

__global__ __launch_bounds__(BLK) void pen_kernel(
    const float* __restrict__ verts, const int* __restrict__ faces,
    const float* __restrict__ prob, const int* __restrict__ nbr,
    const float* __restrict__ nrm, const float* __restrict__ p0s,
    float* __restrict__ partial, int F)
{
    int t = blockIdx.x * BLK + threadIdx.x;
    float val = 0.0f;
    int total = F * KNN;
    if (t < total) {
        int i = t >> 4;
        int j = nbr[t];
        if (j != i) {
            float nx = nrm[3*i+0], ny = nrm[3*i+1], nz = nrm[3*i+2];
            float px = p0s[3*i+0], py = p0s[3*i+1], pz = p0s[3*i+2];
            int j0 = faces[3*j+0], j1 = faces[3*j+1], j2 = faces[3*j+2];
            float ax = verts[3*j0+0], ay = verts[3*j0+1], az = verts[3*j0+2];
            float bx = verts[3*j1+0], by = verts[3*j1+1], bz = verts[3*j1+2];
            float cx = verts[3*j2+0], cy = verts[3*j2+1], cz = verts[3*j2+2];
            bool hit = edge_test(nx,ny,nz, px,py,pz, ax,ay,az, bx,by,bz)
                    || edge_test(nx,ny,nz, px,py,pz, bx,by,bz, cx,cy,cz)
                    || edge_test(nx,ny,nz, px,py,pz, cx,cy,cz, ax,ay,az);
            if (hit) val = prob[j];
        }
    }
    __shared__ float red[BLK];
    red[threadIdx.x] = val;
    __syncthreads();
    #pragma unroll
    for (int s = BLK/2; s > 0; s >>= 1) {
        if (threadIdx.x < s) red[threadIdx.x] += red[threadIdx.x + s];
        __syncthreads();
    }
    if (threadIdx.x == 0) partial[blockIdx.x] = red[0];
}

// ---------------- Kernel 5: final deterministic reduce ----------------
__global__ __launch_bounds__(BLK) void final_reduce(
    const float* __restrict__ partial, int n, float* __restrict__ out, int F)
{
    __shared__ float red[BLK];
    float s = 0.0f;
    for (int i = threadIdx.x; i < n; i += BLK) s += partial[i];
    red[threadIdx.x] = s;
    __syncthreads();
    #pragma unroll
    for (int st = BLK/2; st > 0; st >>= 1) {
        if (threadIdx.x < st) red[threadIdx.x] += red[threadIdx.x + st];
        __syncthreads();
    }
    if (threadIdx.x == 0) out[0] = red[0] / (float)F;
}

extern "C" void kernel_launch(void* const* d_in, const int* in_sizes, int n_in,
                              void* d_out, int out_size, void* d_ws, size_t ws_size,
                              hipStream_t stream)
{
    const float* verts = (const float*)d_in[0];
    const int*   faces = (const int*)d_in[1];
    const float* prob  = (const float*)d_in[2];
    float* out = (float*)d_out;
    int F = in_sizes[2];

    size_t off = 0;
    auto carve = [&](size_t bytes) {
        size_t cur = off;
        off += (bytes + 255) & ~(size_t)255;
        return cur;
    };
    char* w = (char*)d_ws;
    int nPenBlocks = (F * KNN + BLK - 1) / BLK;
    float4* baryq  = (float4*)(w + carve((size_t)F * sizeof(float4)));
    float*  nrm    = (float*)(w + carve((size_t)F * 3 * sizeof(float)));
    float*  p0s    = (float*)(w + carve((size_t)F * 3 * sizeof(float)));
    int*    nbr    = (int*)(w + carve((size_t)F * KNN * sizeof(int)));
    float*  partial= (float*)(w + carve((size_t)nPenBlocks * sizeof(float)));

    // indices-only chunk storage: perChunk = F*KNN*4 bytes
    size_t perChunk = (size_t)F * KNN * sizeof(int) + 512;
    size_t remain = (ws_size > off) ? (ws_size - off) : 0;
    int nchunk = (int)(remain / perChunk);
    if (nchunk > 25) nchunk = 25;
    if (nchunk < 1) nchunk = 1;
    int* cand_i = (int*)(w + carve((size_t)F * KNN * nchunk * sizeof(int)));

    int chunkLen = (F + nchunk - 1) / nchunk;
    int qBlocks = (F + BLK - 1) / BLK;

    prep_kernel<<<qBlocks, BLK, 0, stream>>>(verts, faces, baryq, nrm, p0s, F);
    knn_kernel<<<dim3(qBlocks, nchunk), BLK, 0, stream>>>(
        baryq, cand_i, F, chunkLen, nchunk);
    merge_kernel<<<qBlocks, BLK, 0, stream>>>(baryq, cand_i, nbr, F, nchunk);
    pen_kernel<<<nPenBlocks, BLK, 0, stream>>>(
        verts, faces, prob, nbr, nrm, p0s, partial, F);
    final_reduce<<<1, BLK, 0, stream>>>(partial, nPenBlocks, out, F);
}

// Round 3
// 179.619 us; speedup vs baseline: 8.5529x; 2.5356x over previous
//
#include <hip/hip_runtime.h>
#include <math.h>

#define KNN 16
#define EPS_F 0.001f
#define BLK 256

#define REP16(M) M(0) M(1) M(2) M(3) M(4) M(5) M(6) M(7) \
                 M(8) M(9) M(10) M(11) M(12) M(13) M(14) M(15)

// ---- values-only compare-exchange (2 VALU ops each: v_min/v_max) ----
#define CEA(p,a,b) { float _lo = fminf(p##a, p##b); float _hi = fmaxf(p##a, p##b); p##a = _lo; p##b = _hi; }
#define CED(p,a,b) { float _lo = fminf(p##a, p##b); float _hi = fmaxf(p##a, p##b); p##a = _hi; p##b = _lo; }

// bitonic sort-16 ascending (canonical network, 80 CE)
#define SORT16(p) \
  CEA(p,0,1) CED(p,2,3) CEA(p,4,5) CED(p,6,7) CEA(p,8,9) CED(p,10,11) CEA(p,12,13) CED(p,14,15) \
  CEA(p,0,2) CEA(p,1,3) CED(p,4,6) CED(p,5,7) CEA(p,8,10) CEA(p,9,11) CED(p,12,14) CED(p,13,15) \
  CEA(p,0,1) CEA(p,2,3) CED(p,4,5) CED(p,6,7) CEA(p,8,9) CEA(p,10,11) CED(p,12,13) CED(p,14,15) \
  CEA(p,0,4) CEA(p,1,5) CEA(p,2,6) CEA(p,3,7) CED(p,8,12) CED(p,9,13) CED(p,10,14) CED(p,11,15) \
  CEA(p,0,2) CEA(p,1,3) CEA(p,4,6) CEA(p,5,7) CED(p,8,10) CED(p,9,11) CED(p,12,14) CED(p,13,15) \
  CEA(p,0,1) CEA(p,2,3) CEA(p,4,5) CEA(p,6,7) CED(p,8,9) CED(p,10,11) CED(p,12,13) CED(p,14,15) \
  CEA(p,0,8) CEA(p,1,9) CEA(p,2,10) CEA(p,3,11) CEA(p,4,12) CEA(p,5,13) CEA(p,6,14) CEA(p,7,15) \
  CEA(p,0,4) CEA(p,1,5) CEA(p,2,6) CEA(p,3,7) CEA(p,8,12) CEA(p,9,13) CEA(p,10,14) CEA(p,11,15) \
  CEA(p,0,2) CEA(p,1,3) CEA(p,4,6) CEA(p,5,7) CEA(p,8,10) CEA(p,9,11) CEA(p,12,14) CEA(p,13,15) \
  CEA(p,0,1) CEA(p,2,3) CEA(p,4,5) CEA(p,6,7) CEA(p,8,9) CEA(p,10,11) CEA(p,12,13) CEA(p,14,15)

// bitonic cleanup: input bitonic -> ascending (32 CE)
#define RESORT16(p) \
  CEA(p,0,8) CEA(p,1,9) CEA(p,2,10) CEA(p,3,11) CEA(p,4,12) CEA(p,5,13) CEA(p,6,14) CEA(p,7,15) \
  CEA(p,0,4) CEA(p,1,5) CEA(p,2,6) CEA(p,3,7) CEA(p,8,12) CEA(p,9,13) CEA(p,10,14) CEA(p,11,15) \
  CEA(p,0,2) CEA(p,1,3) CEA(p,4,6) CEA(p,5,7) CEA(p,8,10) CEA(p,9,11) CEA(p,12,14) CEA(p,13,15) \
  CEA(p,0,1) CEA(p,2,3) CEA(p,4,5) CEA(p,6,7) CEA(p,8,9) CEA(p,10,11) CEA(p,12,13) CEA(p,14,15)

// keep 16 smallest of (sorted r) U (sorted x): half-cleaner + cleanup
#define MERGE16(r,x) \
  r##0=fminf(r##0,x##15); r##1=fminf(r##1,x##14); r##2=fminf(r##2,x##13); r##3=fminf(r##3,x##12); \
  r##4=fminf(r##4,x##11); r##5=fminf(r##5,x##10); r##6=fminf(r##6,x##9);  r##7=fminf(r##7,x##8);  \
  r##8=fminf(r##8,x##7);  r##9=fminf(r##9,x##6);  r##10=fminf(r##10,x##5); r##11=fminf(r##11,x##4); \
  r##12=fminf(r##12,x##3); r##13=fminf(r##13,x##2); r##14=fminf(r##14,x##1); r##15=fminf(r##15,x##0); \
  RESORT16(r)

// int compare-exchange for tie sorting
#define CEAI(p,a,b) { int _lo = min(p##a, p##b); int _hi = max(p##a, p##b); p##a = _lo; p##b = _hi; }
#define CEDI(p,a,b) { int _lo = min(p##a, p##b); int _hi = max(p##a, p##b); p##a = _hi; p##b = _lo; }
#define SORT8I(p) \
  CEAI(p,0,1) CEDI(p,2,3) CEAI(p,4,5) CEDI(p,6,7) \
  CEAI(p,0,2) CEAI(p,1,3) CEDI(p,4,6) CEDI(p,5,7) \
  CEAI(p,0,1) CEAI(p,2,3) CEDI(p,4,5) CEDI(p,6,7) \
  CEAI(p,0,4) CEAI(p,1,5) CEAI(p,2,6) CEAI(p,3,7) \
  CEAI(p,0,2) CEAI(p,1,3) CEAI(p,4,6) CEAI(p,5,7) \
  CEAI(p,0,1) CEAI(p,2,3) CEAI(p,4,5) CEAI(p,6,7)

// single shared distance fn -> identical codegen in both passes
__device__ __forceinline__ float dist2(float4 q, float4 p) {
    return (q.w + p.w) - 2.0f * (q.x*p.x + q.y*p.y + q.z*p.z);
}

// ---------------- Kernel 1: per-face prep ----------------
__global__ __launch_bounds__(BLK) void prep_kernel(
    const float* __restrict__ verts, const int* __restrict__ faces,
    float4* __restrict__ baryq, float* __restrict__ nrm,
    float* __restrict__ p0s, int F)
{
    int f = blockIdx.x * BLK + threadIdx.x;
    if (f >= F) return;
    int i0 = faces[3*f+0], i1 = faces[3*f+1], i2 = faces[3*f+2];
    float ax = verts[3*i0+0], ay = verts[3*i0+1], az = verts[3*i0+2];
    float bx = verts[3*i1+0], by = verts[3*i1+1], bz = verts[3*i1+2];
    float cx = verts[3*i2+0], cy = verts[3*i2+1], cz = verts[3*i2+2];
    float gx = (ax + bx + cx) / 3.0f;
    float gy = (ay + by + cy) / 3.0f;
    float gz = (az + bz + cz) / 3.0f;
    float sq = gx*gx + gy*gy + gz*gz;
    baryq[f] = make_float4(gx, gy, gz, sq);
    float e1x = bx-ax, e1y = by-ay, e1z = bz-az;
    float e2x = cx-ax, e2y = cy-ay, e2z = cz-az;
    float nx = e1y*e2z - e1z*e2y;
    float ny = e1z*e2x - e1x*e2z;
    float nz = e1x*e2y - e1y*e2x;
    float len = sqrtf(nx*nx + ny*ny + nz*nz);
    float dn = fmaxf(len, 1e-12f);
    nrm[3*f+0] = nx/dn; nrm[3*f+1] = ny/dn; nrm[3*f+2] = nz/dn;
    p0s[3*f+0] = ax; p0s[3*f+1] = ay; p0s[3*f+2] = az;
}

// ---------------- Kernel 2: chunked top-16 VALUES via bitonic tiles --------
// grid (ceil(F/BLK), nchunk). Output per chunk: 16 sorted d2 values, stored
// transposed cand_d[(chunk*16+k)*F + qi] (coalesced).
__global__ __launch_bounds__(BLK) void knn_vals(
    const float4* __restrict__ baryq, float* __restrict__ cand_d,
    int F, int chunkLen)
{
    __shared__ float4 sb[BLK];
    int tid = threadIdx.x;
    int qi = blockIdx.x * BLK + tid;
    int qc = min(qi, F-1);
    float4 q = baryq[qc];
    #define DECLR(m) float r##m = INFINITY;
    REP16(DECLR)
    #undef DECLR
    int jb = blockIdx.y * chunkLen;
    int je = min(jb + chunkLen, F);
    for (int base = jb; base < je; base += BLK) {
        int j = base + tid;
        sb[tid] = (j < je) ? baryq[j] : make_float4(0.f, 0.f, 0.f, INFINITY);
        __syncthreads();
        #pragma unroll 1
        for (int g = 0; g < BLK; g += 16) {
            float x0  = dist2(q, sb[g+0]);
            float x1  = dist2(q, sb[g+1]);
            float x2  = dist2(q, sb[g+2]);
            float x3  = dist2(q, sb[g+3]);
            float x4  = dist2(q, sb[g+4]);
            float x5  = dist2(q, sb[g+5]);
            float x6  = dist2(q, sb[g+6]);
            float x7  = dist2(q, sb[g+7]);
            float x8  = dist2(q, sb[g+8]);
            float x9  = dist2(q, sb[g+9]);
            float x10 = dist2(q, sb[g+10]);
            float x11 = dist2(q, sb[g+11]);
            float x12 = dist2(q, sb[g+12]);
            float x13 = dist2(q, sb[g+13]);
            float x14 = dist2(q, sb[g+14]);
            float x15 = dist2(q, sb[g+15]);
            SORT16(x)
            MERGE16(r, x)
        }
        __syncthreads();
    }
    if (qi < F) {
        size_t cb = (size_t)blockIdx.y * KNN * F + qi;
        #define STR(m) cand_d[cb + (size_t)(m) * F] = r##m;
        REP16(STR)
        #undef STR
    }
}

// ---------------- Kernel 3: merge sorted chunk lists -> d16; zero counters -
__global__ __launch_bounds__(BLK) void merge_d16(
    const float* __restrict__ cand_d, float* __restrict__ d16,
    int* __restrict__ cntS, int* __restrict__ cntT, int F, int nchunk)
{
    int qi = blockIdx.x * BLK + threadIdx.x;
    if (qi >= F) return;
    cntS[qi] = 0; cntT[qi] = 0;
    #define LDR(m) float r##m = cand_d[(size_t)(m) * F + qi];
    REP16(LDR)
    #undef LDR
    for (int c = 1; c < nchunk; ++c) {
        size_t cb = (size_t)c * KNN * F + qi;
        #define LDX(m) float x##m = cand_d[cb + (size_t)(m) * F];
        REP16(LDX)
        #undef LDX
        MERGE16(r, x)
    }
    d16[qi] = r15;
}

// ---------------- Kernel 4: threshold rescan, collect indices --------------
__global__ __launch_bounds__(BLK) void collect_kernel(
    const float4* __restrict__ baryq, const float* __restrict__ d16,
    int* __restrict__ cntS, int* __restrict__ cntT,
    int* __restrict__ nbrS, int* __restrict__ tieI,
    int F, int chunkLen)
{
    __shared__ float4 sb[BLK];
    int tid = threadIdx.x;
    int qi = blockIdx.x * BLK + tid;
    bool active = qi < F;
    int qc = active ? qi : 0;
    float4 q = baryq[qc];
    float dth = active ? d16[qc] : -INFINITY;
    int jb = blockIdx.y * chunkLen;
    int je = min(jb + chunkLen, F);
    for (int base = jb; base < je; base += BLK) {
        int j = base + tid;
        sb[tid] = (j < je) ? baryq[j] : make_float4(0.f, 0.f, 0.f, INFINITY);
        __syncthreads();
        #pragma unroll 4
        for (int jj = 0; jj < BLK; ++jj) {
            float d2 = dist2(q, sb[jj]);
            if (d2 <= dth) {
                int cj = base + jj;
                if (d2 < dth) {
                    int pos = atomicAdd(&cntS[qi], 1);
                    if (pos < 16) nbrS[qi * 16 + pos] = cj;
                } else {
                    int pos = atomicAdd(&cntT[qi], 1);
                    if (pos < 8) tieI[qi * 8 + pos] = cj;
                }
            }
        }
        __syncthreads();
    }
}

// ---------------- Kernel 5: finalize neighbor lists ------------------------
__global__ __launch_bounds__(BLK) void finalize_nbr(
    const int* __restrict__ cntS, const int* __restrict__ cntT,
    const int* __restrict__ nbrS, const int* __restrict__ tieI,
    int* __restrict__ nbr, int F)
{
    int qi = blockIdx.x * BLK + threadIdx.x;
    if (qi >= F) return;
    int S = min(cntS[qi], 16);
    int T = min(cntT[qi], 8);
    int t0 = (0 < T) ? tieI[qi*8+0] : 0x7fffffff;
    int t1 = (1 < T) ? tieI[qi*8+1] : 0x7fffffff;
    int t2 = (2 < T) ? tieI[qi*8+2] : 0x7fffffff;
    int t3 = (3 < T) ? tieI[qi*8+3] : 0x7fffffff;
    int t4 = (4 < T) ? tieI[qi*8+4] : 0x7fffffff;
    int t5 = (5 < T) ? tieI[qi*8+5] : 0x7fffffff;
    int t6 = (6 < T) ? tieI[qi*8+6] : 0x7fffffff;
    int t7 = (7 < T) ? tieI[qi*8+7] : 0x7fffffff;
    SORT8I(t)   // ties ascending by index (lax.top_k stable-order semantics)
    for (int w = 0; w < S; ++w) nbr[qi*16 + w] = nbrS[qi*16 + w];
    int take = min(16 - S, T);
    #define APPT(k) if ((k) < take) nbr[qi*16 + S + (k)] = t##k;
    APPT(0) APPT(1) APPT(2) APPT(3) APPT(4) APPT(5) APPT(6) APPT(7)
    #undef APPT
    for (int w = S + take; w < 16; ++w) nbr[qi*16 + w] = qi;  // self-pad, masked in pen
}

// ---------------- Kernel 6: edge-plane penetration + partial sums ----------
__device__ __forceinline__ bool edge_test(
    float nx, float ny, float nz, float px, float py, float pz,
    float ax, float ay, float az, float bx, float by, float bz)
{
    float denom = nx*(bx-ax) + ny*(by-ay) + nz*(bz-az);
    if (fabsf(denom) < EPS_F) return false;
    float numer = nx*(px-ax) + ny*(py-ay) + nz*(pz-az);
    float t = numer / denom;
    return (t > 0.0f) && (t < 1.0f);
}

__global__ __launch_bounds__(BLK) void pen_kernel(
    const float* __restrict__ verts, const int* __restrict__ faces,
    const float* __restrict__ prob, const int* __restrict__ nbr,
    const float* __restrict__ nrm, const float* __restrict__ p0s,
    float* __restrict__ partial, int F)
{
    int t = blockIdx.x * BLK + threadIdx.x;
    float val = 0.0f;
    int total = F * KNN;
    if (t < total) {
        int i = t >> 4;
        int j = nbr[t];
        if (j != i) {
            float nx = nrm[3*i+0], ny = nrm[3*i+1], nz = nrm[3*i+2];
            float px = p0s[3*i+0], py = p0s[3*i+1], pz = p0s[3*i+2];
            int j0 = faces[3*j+0], j1 = faces[3*j+1], j2 = faces[3*j+2];
            float ax = verts[3*j0+0], ay = verts[3*j0+1], az = verts[3*j0+2];
            float bx = verts[3*j1+0], by = verts[3*j1+1], bz = verts[3*j1+2];
            float cx = verts[3*j2+0], cy = verts[3*j2+1], cz = verts[3*j2+2];
            bool hit = edge_test(nx,ny,nz, px,py,pz, ax,ay,az, bx,by,bz)
                    || edge_test(nx,ny,nz, px,py,pz, bx,by,bz, cx,cy,cz)
                    || edge_test(nx,ny,nz, px,py,pz, cx,cy,cz, ax,ay,az);
            if (hit) val = prob[j];
        }
    }
    __shared__ float red[BLK];
    red[threadIdx.x] = val;
    __syncthreads();
    #pragma unroll
    for (int s = BLK/2; s > 0; s >>= 1) {
        if (threadIdx.x < s) red[threadIdx.x] += red[threadIdx.x + s];
        __syncthreads();
    }
    if (threadIdx.x == 0) partial[blockIdx.x] = red[0];
}

// ---------------- Kernel 7: final deterministic reduce ----------------
__global__ __launch_bounds__(BLK) void final_reduce(
    const float* __restrict__ partial, int n, float* __restrict__ out, int F)
{
    __shared__ float red[BLK];
    float s = 0.0f;
    for (int i = threadIdx.x; i < n; i += BLK) s += partial[i];
    red[threadIdx.x] = s;
    __syncthreads();
    #pragma unroll
    for (int st = BLK/2; st > 0; st >>= 1) {
        if (threadIdx.x < st) red[threadIdx.x] += red[threadIdx.x + st];
        __syncthreads();
    }
    if (threadIdx.x == 0) out[0] = red[0] / (float)F;
}

extern "C" void kernel_launch(void* const* d_in, const int* in_sizes, int n_in,
                              void* d_out, int out_size, void* d_ws, size_t ws_size,
                              hipStream_t stream)
{
    const float* verts = (const float*)d_in[0];
    const int*   faces = (const int*)d_in[1];
    const float* prob  = (const float*)d_in[2];
    float* out = (float*)d_out;
    int F = in_sizes[2];

    size_t off = 0;
    auto carve = [&](size_t bytes) {
        size_t cur = off;
        off += (bytes + 255) & ~(size_t)255;
        return cur;
    };
    char* w = (char*)d_ws;
    int nPenBlocks = (F * KNN + BLK - 1) / BLK;
    float4* baryq  = (float4*)(w + carve((size_t)F * sizeof(float4)));
    float*  nrm    = (float*)(w + carve((size_t)F * 3 * sizeof(float)));
    float*  p0s    = (float*)(w + carve((size_t)F * 3 * sizeof(float)));
    int*    nbr    = (int*)(w + carve((size_t)F * KNN * sizeof(int)));
    float*  partial= (float*)(w + carve((size_t)nPenBlocks * sizeof(float)));
    float*  d16    = (float*)(w + carve((size_t)F * sizeof(float)));
    int*    cntS   = (int*)(w + carve((size_t)F * sizeof(int)));
    int*    cntT   = (int*)(w + carve((size_t)F * sizeof(int)));
    int*    nbrS   = (int*)(w + carve((size_t)F * 16 * sizeof(int)));
    int*    tieI   = (int*)(w + carve((size_t)F * 8 * sizeof(int)));

    // chunk count from remaining workspace; chunkLen multiple of BLK to avoid
    // padded-tile waste (pad candidates cost full sort-network work)
    size_t perChunk = (size_t)F * KNN * sizeof(float) + 512;
    size_t remain = (ws_size > off) ? (ws_size - off) : 0;
    int nchunk = (int)(remain / perChunk);
    if (nchunk > 20) nchunk = 20;
    if (nchunk < 1) nchunk = 1;
    int chunkLen = (F + nchunk - 1) / nchunk;
    chunkLen = ((chunkLen + BLK - 1) / BLK) * BLK;
    nchunk = (F + chunkLen - 1) / chunkLen;   // drop empty chunks
    float* cand_d = (float*)(w + carve((size_t)F * KNN * nchunk * sizeof(float)));

    int qBlocks = (F + BLK - 1) / BLK;

    prep_kernel<<<qBlocks, BLK, 0, stream>>>(verts, faces, baryq, nrm, p0s, F);
    knn_vals<<<dim3(qBlocks, nchunk), BLK, 0, stream>>>(baryq, cand_d, F, chunkLen);
    merge_d16<<<qBlocks, BLK, 0, stream>>>(cand_d, d16, cntS, cntT, F, nchunk);
    collect_kernel<<<dim3(qBlocks, nchunk), BLK, 0, stream>>>(
        baryq, d16, cntS, cntT, nbrS, tieI, F, chunkLen);
    finalize_nbr<<<qBlocks, BLK, 0, stream>>>(cntS, cntT, nbrS, tieI, nbr, F);
    pen_kernel<<<nPenBlocks, BLK, 0, stream>>>(
        verts, faces, prob, nbr, nrm, p0s, partial, F);
    final_reduce<<<1, BLK, 0, stream>>>(partial, nPenBlocks, out, F);
}

// Round 4
// 96.355 us; speedup vs baseline: 15.9437x; 1.8641x over previous
//
#include <hip/hip_runtime.h>
#include <math.h>

#define KNN 16
#define EPS_F 0.001f
#define BLK 256

#define REP16(M) M(0) M(1) M(2) M(3) M(4) M(5) M(6) M(7) \
                 M(8) M(9) M(10) M(11) M(12) M(13) M(14) M(15)

// ---- int compare-exchange (v_min_i32/v_max_i32, 2 ops) ----
// keys are float bit patterns with idx in low 14 bits; same-sign IEEE floats
// order correctly as signed ints; negative (self-dist ~ -0) keys sort first,
// which is fine (self is masked later; in-list order is irrelevant).
#define CEAI(p,a,b) { int _lo = min(p##a, p##b); int _hi = max(p##a, p##b); p##a = _lo; p##b = _hi; }
#define CEDI(p,a,b) { int _lo = min(p##a, p##b); int _hi = max(p##a, p##b); p##a = _hi; p##b = _lo; }

// bitonic sort-16 ascending (canonical network, 80 CE)
#define SORT16I(p) \
  CEAI(p,0,1) CEDI(p,2,3) CEAI(p,4,5) CEDI(p,6,7) CEAI(p,8,9) CEDI(p,10,11) CEAI(p,12,13) CEDI(p,14,15) \
  CEAI(p,0,2) CEAI(p,1,3) CEDI(p,4,6) CEDI(p,5,7) CEAI(p,8,10) CEAI(p,9,11) CEDI(p,12,14) CEDI(p,13,15) \
  CEAI(p,0,1) CEAI(p,2,3) CEDI(p,4,5) CEDI(p,6,7) CEAI(p,8,9) CEAI(p,10,11) CEDI(p,12,13) CEDI(p,14,15) \
  CEAI(p,0,4) CEAI(p,1,5) CEAI(p,2,6) CEAI(p,3,7) CEDI(p,8,12) CEDI(p,9,13) CEDI(p,10,14) CEDI(p,11,15) \
  CEAI(p,0,2) CEAI(p,1,3) CEAI(p,4,6) CEAI(p,5,7) CEDI(p,8,10) CEDI(p,9,11) CEDI(p,12,14) CEDI(p,13,15) \
  CEAI(p,0,1) CEAI(p,2,3) CEAI(p,4,5) CEAI(p,6,7) CEDI(p,8,9) CEDI(p,10,11) CEDI(p,12,13) CEDI(p,14,15) \
  CEAI(p,0,8) CEAI(p,1,9) CEAI(p,2,10) CEAI(p,3,11) CEAI(p,4,12) CEAI(p,5,13) CEAI(p,6,14) CEAI(p,7,15) \
  CEAI(p,0,4) CEAI(p,1,5) CEAI(p,2,6) CEAI(p,3,7) CEAI(p,8,12) CEAI(p,9,13) CEAI(p,10,14) CEAI(p,11,15) \
  CEAI(p,0,2) CEAI(p,1,3) CEAI(p,4,6) CEAI(p,5,7) CEAI(p,8,10) CEAI(p,9,11) CEAI(p,12,14) CEAI(p,13,15) \
  CEAI(p,0,1) CEAI(p,2,3) CEAI(p,4,5) CEAI(p,6,7) CEAI(p,8,9) CEAI(p,10,11) CEAI(p,12,13) CEAI(p,14,15)

// bitonic cleanup: bitonic input -> ascending (32 CE)
#define RESORT16I(p) \
  CEAI(p,0,8) CEAI(p,1,9) CEAI(p,2,10) CEAI(p,3,11) CEAI(p,4,12) CEAI(p,5,13) CEAI(p,6,14) CEAI(p,7,15) \
  CEAI(p,0,4) CEAI(p,1,5) CEAI(p,2,6) CEAI(p,3,7) CEAI(p,8,12) CEAI(p,9,13) CEAI(p,10,14) CEAI(p,11,15) \
  CEAI(p,0,2) CEAI(p,1,3) CEAI(p,4,6) CEAI(p,5,7) CEAI(p,8,10) CEAI(p,9,11) CEAI(p,12,14) CEAI(p,13,15) \
  CEAI(p,0,1) CEAI(p,2,3) CEAI(p,4,5) CEAI(p,6,7) CEAI(p,8,9) CEAI(p,10,11) CEAI(p,12,13) CEAI(p,14,15)

// keep 16 smallest of (sorted r) U (sorted x): half-cleaner + cleanup
#define MERGE16I(r,x) \
  r##0=min(r##0,x##15); r##1=min(r##1,x##14); r##2=min(r##2,x##13); r##3=min(r##3,x##12); \
  r##4=min(r##4,x##11); r##5=min(r##5,x##10); r##6=min(r##6,x##9);  r##7=min(r##7,x##8);  \
  r##8=min(r##8,x##7);  r##9=min(r##9,x##6);  r##10=min(r##10,x##5); r##11=min(r##11,x##4); \
  r##12=min(r##12,x##3); r##13=min(r##13,x##2); r##14=min(r##14,x##1); r##15=min(r##15,x##0); \
  RESORT16I(r)

// shared distance fn -> identical codegen everywhere (matches ref formula)
__device__ __forceinline__ float dist2(float4 q, float4 p) {
    return (q.w + p.w) - 2.0f * (q.x*p.x + q.y*p.y + q.z*p.z);
}

// pack: truncate mantissa to 9 bits, put candidate index in low 14 bits.
// single v_and_or_b32. lexicographic (d2_trunc, idx) ordering.
__device__ __forceinline__ int packkey(float d2, int j) {
    return (__float_as_int(d2) & 0xFFFFC000) | j;
}

// ---------------- Kernel 1: per-face prep ----------------
__global__ __launch_bounds__(BLK) void prep_kernel(
    const float* __restrict__ verts, const int* __restrict__ faces,
    float4* __restrict__ baryq, float* __restrict__ nrm,
    float* __restrict__ p0s, int F)
{
    int f = blockIdx.x * BLK + threadIdx.x;
    if (f >= F) return;
    int i0 = faces[3*f+0], i1 = faces[3*f+1], i2 = faces[3*f+2];
    float ax = verts[3*i0+0], ay = verts[3*i0+1], az = verts[3*i0+2];
    float bx = verts[3*i1+0], by = verts[3*i1+1], bz = verts[3*i1+2];
    float cx = verts[3*i2+0], cy = verts[3*i2+1], cz = verts[3*i2+2];
    float gx = (ax + bx + cx) / 3.0f;
    float gy = (ay + by + cy) / 3.0f;
    float gz = (az + bz + cz) / 3.0f;
    float sq = gx*gx + gy*gy + gz*gz;
    baryq[f] = make_float4(gx, gy, gz, sq);
    float e1x = bx-ax, e1y = by-ay, e1z = bz-az;
    float e2x = cx-ax, e2y = cy-ay, e2z = cz-az;
    float nx = e1y*e2z - e1z*e2y;
    float ny = e1z*e2x - e1x*e2z;
    float nz = e1x*e2y - e1y*e2x;
    float len = sqrtf(nx*nx + ny*ny + nz*nz);
    float dn = fmaxf(len, 1e-12f);
    nrm[3*f+0] = nx/dn; nrm[3*f+1] = ny/dn; nrm[3*f+2] = nz/dn;
    p0s[3*f+0] = ax; p0s[3*f+1] = ay; p0s[3*f+2] = az;
}

// ---------------- Kernel 2: chunked top-16 packed KEYS via bitonic tiles ---
// grid (ceil(F/BLK), nchunk). Output: 16 sorted keys per (query, chunk),
// transposed cand_k[(chunk*16+k)*F + qi] (coalesced).
__global__ __launch_bounds__(BLK) void knn_keys(
    const float4* __restrict__ baryq, int* __restrict__ cand_k,
    int F, int chunkLen)
{
    __shared__ float4 sb[BLK];
    int tid = threadIdx.x;
    int qi = blockIdx.x * BLK + tid;
    int qc = min(qi, F-1);
    float4 q = baryq[qc];
    #define DECLR(m) int r##m = 0x7fffffff;
    REP16(DECLR)
    #undef DECLR
    int jb = blockIdx.y * chunkLen;
    int je = min(jb + chunkLen, F);
    for (int base = jb; base < je; base += BLK) {
        int j = base + tid;
        sb[tid] = (j < je) ? baryq[j] : make_float4(0.f, 0.f, 0.f, INFINITY);
        __syncthreads();
        #pragma unroll 1
        for (int g = 0; g < BLK; g += 16) {
            #define MKKEY(m) int x##m = packkey(dist2(q, sb[g+(m)]), base+g+(m));
            REP16(MKKEY)
            #undef MKKEY
            SORT16I(x)
            MERGE16I(r, x)
        }
        __syncthreads();
    }
    if (qi < F) {
        size_t cb = (size_t)blockIdx.y * KNN * F + qi;
        #define STR(m) cand_k[cb + (size_t)(m) * F] = r##m;
        REP16(STR)
        #undef STR
    }
}

// ---------------- Kernel 3: merge sorted chunk key-lists -> nbr indices ----
__global__ __launch_bounds__(BLK) void merge_nbr(
    const int* __restrict__ cand_k, int* __restrict__ nbr, int F, int nchunk)
{
    int qi = blockIdx.x * BLK + threadIdx.x;
    if (qi >= F) return;
    #define LDR(m) int r##m = cand_k[(size_t)(m) * F + qi];
    REP16(LDR)
    #undef LDR
    for (int c = 1; c < nchunk; ++c) {
        size_t cb = (size_t)c * KNN * F + qi;
        #define LDX(m) int x##m = cand_k[cb + (size_t)(m) * F];
        REP16(LDX)
        #undef LDX
        MERGE16I(r, x)
    }
    size_t ob = (size_t)qi * KNN;
    #define STN(m) nbr[ob + (m)] = r##m & 0x3FFF;
    REP16(STN)
    #undef STN
}

// ---------------- Kernel 4: edge-plane penetration + partial sums ----------
__device__ __forceinline__ bool edge_test(
    float nx, float ny, float nz, float px, float py, float pz,
    float ax, float ay, float az, float bx, float by, float bz)
{
    float denom = nx*(bx-ax) + ny*(by-ay) + nz*(bz-az);
    if (fabsf(denom) < EPS_F) return false;
    float numer = nx*(px-ax) + ny*(py-ay) + nz*(pz-az);
    float t = numer / denom;
    return (t > 0.0f) && (t < 1.0f);
}

__global__ __launch_bounds__(BLK) void pen_kernel(
    const float* __restrict__ verts, const int* __restrict__ faces,
    const float* __restrict__ prob, const int* __restrict__ nbr,
    const float* __restrict__ nrm, const float* __restrict__ p0s,
    float* __restrict__ partial, int F)
{
    int t = blockIdx.x * BLK + threadIdx.x;
    float val = 0.0f;
    int total = F * KNN;
    if (t < total) {
        int i = t >> 4;
        int j = nbr[t];
        if (j != i) {
            float nx = nrm[3*i+0], ny = nrm[3*i+1], nz = nrm[3*i+2];
            float px = p0s[3*i+0], py = p0s[3*i+1], pz = p0s[3*i+2];
            int j0 = faces[3*j+0], j1 = faces[3*j+1], j2 = faces[3*j+2];
            float ax = verts[3*j0+0], ay = verts[3*j0+1], az = verts[3*j0+2];
            float bx = verts[3*j1+0], by = verts[3*j1+1], bz = verts[3*j1+2];
            float cx = verts[3*j2+0], cy = verts[3*j2+1], cz = verts[3*j2+2];
            bool hit = edge_test(nx,ny,nz, px,py,pz, ax,ay,az, bx,by,bz)
                    || edge_test(nx,ny,nz, px,py,pz, bx,by,bz, cx,cy,cz)
                    || edge_test(nx,ny,nz, px,py,pz, cx,cy,cz, ax,ay,az);
            if (hit) val = prob[j];
        }
    }
    __shared__ float red[BLK];
    red[threadIdx.x] = val;
    __syncthreads();
    #pragma unroll
    for (int s = BLK/2; s > 0; s >>= 1) {
        if (threadIdx.x < s) red[threadIdx.x] += red[threadIdx.x + s];
        __syncthreads();
    }
    if (threadIdx.x == 0) partial[blockIdx.x] = red[0];
}

// ---------------- Kernel 5: final deterministic reduce ----------------
__global__ __launch_bounds__(BLK) void final_reduce(
    const float* __restrict__ partial, int n, float* __restrict__ out, int F)
{
    __shared__ float red[BLK];
    float s = 0.0f;
    for (int i = threadIdx.x; i < n; i += BLK) s += partial[i];
    red[threadIdx.x] = s;
    __syncthreads();
    #pragma unroll
    for (int st = BLK/2; st > 0; st >>= 1) {
        if (threadIdx.x < st) red[threadIdx.x] += red[threadIdx.x + st];
        __syncthreads();
    }
    if (threadIdx.x == 0) out[0] = red[0] / (float)F;
}

extern "C" void kernel_launch(void* const* d_in, const int* in_sizes, int n_in,
                              void* d_out, int out_size, void* d_ws, size_t ws_size,
                              hipStream_t stream)
{
    const float* verts = (const float*)d_in[0];
    const int*   faces = (const int*)d_in[1];
    const float* prob  = (const float*)d_in[2];
    float* out = (float*)d_out;
    int F = in_sizes[2];

    size_t off = 0;
    auto carve = [&](size_t bytes) {
        size_t cur = off;
        off += (bytes + 255) & ~(size_t)255;
        return cur;
    };
    char* w = (char*)d_ws;
    int nPenBlocks = (F * KNN + BLK - 1) / BLK;
    float4* baryq  = (float4*)(w + carve((size_t)F * sizeof(float4)));
    float*  nrm    = (float*)(w + carve((size_t)F * 3 * sizeof(float)));
    float*  p0s    = (float*)(w + carve((size_t)F * 3 * sizeof(float)));
    int*    nbr    = (int*)(w + carve((size_t)F * KNN * sizeof(int)));
    float*  partial= (float*)(w + carve((size_t)nPenBlocks * sizeof(float)));

    // chunk count from remaining workspace; chunkLen multiple of BLK.
    // cap 40 -> chunkLen 256 at F=10000: 1600 blocks = 6.25/CU (load balance).
    size_t perChunk = (size_t)F * KNN * sizeof(int) + 512;
    size_t remain = (ws_size > off) ? (ws_size - off) : 0;
    int nchunk = (int)(remain / perChunk);
    if (nchunk > 40) nchunk = 40;
    if (nchunk < 1) nchunk = 1;
    int chunkLen = (F + nchunk - 1) / nchunk;
    chunkLen = ((chunkLen + BLK - 1) / BLK) * BLK;
    nchunk = (F + chunkLen - 1) / chunkLen;   // drop empty chunks
    int* cand_k = (int*)(w + carve((size_t)F * KNN * nchunk * sizeof(int)));

    int qBlocks = (F + BLK - 1) / BLK;

    prep_kernel<<<qBlocks, BLK, 0, stream>>>(verts, faces, baryq, nrm, p0s, F);
    knn_keys<<<dim3(qBlocks, nchunk), BLK, 0, stream>>>(baryq, cand_k, F, chunkLen);
    merge_nbr<<<qBlocks, BLK, 0, stream>>>(cand_k, nbr, F, nchunk);
    pen_kernel<<<nPenBlocks, BLK, 0, stream>>>(
        verts, faces, prob, nbr, nrm, p0s, partial, F);
    final_reduce<<<1, BLK, 0, stream>>>(partial, nPenBlocks, out, F);
}